// Round 8
// baseline (11989.256 us; speedup 1.0000x reference)
//
#include <hip/hip_runtime.h>
#include <math.h>

#define LEAKY(t) ((t) >= 0.0f ? (t) : 0.01f * (t))

static __device__ __forceinline__ float b2f(unsigned short u) {
    return __uint_as_float(((unsigned)u) << 16);
}
static __device__ __forceinline__ unsigned short f2b(float f) {
    unsigned x = __float_as_uint(f);
    unsigned r = (x + 0x7fffu + ((x >> 16) & 1u)) >> 16;
    return (unsigned short)r;
}

// ---------------- init helpers ----------------

__global__ void k_seti(int* __restrict__ p, int v, int n) {
    int i = blockIdx.x * blockDim.x + threadIdx.x;
    int st = gridDim.x * blockDim.x;
    for (; i < n; i += st) p[i] = v;
}

__global__ void k_setf(float* __restrict__ p, float v, int n) {
    int i = blockIdx.x * blockDim.x + threadIdx.x;
    int st = gridDim.x * blockDim.x;
    for (; i < n; i += st) p[i] = v;
}

__global__ void k_stash_f32(const float* __restrict__ a, int i0, int i1, int i2, int i3,
                            float* __restrict__ dst) {
    if (threadIdx.x == 0 && blockIdx.x == 0) {
        dst[0] = a[i0]; dst[1] = a[i1]; dst[2] = a[i2]; dst[3] = a[i3];
    }
}

__global__ void k_stash_b16(const unsigned short* __restrict__ a, int i0, int i1, int i2, int i3,
                            float* __restrict__ dst) {
    if (threadIdx.x == 0 && blockIdx.x == 0) {
        dst[0] = b2f(a[i0]); dst[1] = b2f(a[i1]); dst[2] = b2f(a[i2]); dst[3] = b2f(a[i3]);
    }
}

// ---------------- edge dtype detection ----------------

__global__ void k_detect(const int* __restrict__ ei, int* __restrict__ flag) {
    __shared__ int nz;
    if (threadIdx.x == 0) nz = 0;
    __syncthreads();
    int acc = 0;
    for (int i = threadIdx.x; i < 1024; i += 256) acc |= ei[2 * i + 1];
    if (acc != 0) atomicOr(&nz, 1);
    __syncthreads();
    if (threadIdx.x == 0) *flag = (nz == 0) ? 1 : 0;
}

// ---------------- CSR build ----------------

__global__ void k_count(const int* __restrict__ ei, int E, int Nn,
                        const int* __restrict__ flag, int* __restrict__ cnt) {
    int f = *flag;
    int i = blockIdx.x * blockDim.x + threadIdx.x;
    int stride = gridDim.x * blockDim.x;
    for (; i < E; i += stride) {
        int d = f ? ei[2 * E + 2 * i] : ei[E + i];
        if ((unsigned)d < (unsigned)Nn) atomicAdd(&cnt[d], 1);
    }
}

__global__ void k_dinv(const int* __restrict__ cnt, float* __restrict__ dinv, int n) {
    int i = blockIdx.x * blockDim.x + threadIdx.x;
    if (i < n) dinv[i] = rsqrtf((float)(cnt[i] + 1));
}

__global__ void k_scan(const int* __restrict__ cnt, int* __restrict__ start, int n) {
    __shared__ int sm[256];
    __shared__ int carry;
    int tid = threadIdx.x;
    if (tid == 0) carry = 0;
    __syncthreads();
    for (int base = 0; base < n; base += 1024) {
        int i0 = base + tid * 4;
        int v0 = (i0 + 0 < n) ? cnt[i0 + 0] : 0;
        int v1 = (i0 + 1 < n) ? cnt[i0 + 1] : 0;
        int v2 = (i0 + 2 < n) ? cnt[i0 + 2] : 0;
        int v3 = (i0 + 3 < n) ? cnt[i0 + 3] : 0;
        int s = v0 + v1 + v2 + v3;
        sm[tid] = s;
        __syncthreads();
        int x = s;
        for (int off = 1; off < 256; off <<= 1) {
            int y = (tid >= off) ? sm[tid - off] : 0;
            __syncthreads();
            x += y;
            sm[tid] = x;
            __syncthreads();
        }
        int e = x - s + carry;
        if (i0 + 0 < n) start[i0 + 0] = e; e += v0;
        if (i0 + 1 < n) start[i0 + 1] = e; e += v1;
        if (i0 + 2 < n) start[i0 + 2] = e; e += v2;
        if (i0 + 3 < n) start[i0 + 3] = e; e += v3;
        __syncthreads();
        if (tid == 255) carry += sm[255];
        __syncthreads();
    }
    if (tid == 0) start[n] = carry;
}

__global__ void k_copy_i32(const int* __restrict__ a, int* __restrict__ b, int n) {
    int i = blockIdx.x * blockDim.x + threadIdx.x;
    if (i < n) b[i] = a[i];
}

__global__ void k_fill(const int* __restrict__ ei, int E, int Nn,
                       const int* __restrict__ flag,
                       int* __restrict__ cursor, int* __restrict__ srcS) {
    int f = *flag;
    int i = blockIdx.x * blockDim.x + threadIdx.x;
    int stride = gridDim.x * blockDim.x;
    for (; i < E; i += stride) {
        int s = f ? ei[2 * i] : ei[i];
        int d = f ? ei[2 * E + 2 * i] : ei[E + i];
        if ((unsigned)d < (unsigned)Nn) {
            int p = atomicAdd(&cursor[d], 1);
            srcS[p] = ((unsigned)s < (unsigned)Nn) ? s : 0;
        }
    }
}

// ---------------- aggregation ----------------
// layer 1: fp32 in (x), fp32 out (T1), F=128

__global__ void k_agg1(const float* __restrict__ x, const float* __restrict__ dinv,
                       const int* __restrict__ start, const int* __restrict__ srcS,
                       float* __restrict__ out, int M) {
    int t = threadIdx.x;  // 128
    for (int n = blockIdx.x; n < M; n += gridDim.x) {
        float di = dinv[n];
        float a = x[(size_t)n * 128 + t] * di;
        int e1 = start[n + 1];
        for (int j = start[n]; j < e1; ++j) {
            int s = srcS[j];
            a += x[(size_t)s * 128 + t] * dinv[s];
        }
        out[(size_t)n * 128 + t] = a * di;
    }
}

// layer 2: bf16 in (Y1), bf16 out (T2), F=256

__global__ void k_agg2(const unsigned short* __restrict__ Y1, const float* __restrict__ dinv,
                       const int* __restrict__ start, const int* __restrict__ srcS,
                       unsigned short* __restrict__ T2, int M) {
    int t = threadIdx.x;  // 256
    for (int n = blockIdx.x; n < M; n += gridDim.x) {
        float di = dinv[n];
        float a = b2f(Y1[(size_t)n * 256 + t]) * di;
        int e1 = start[n + 1];
        for (int j = start[n]; j < e1; ++j) {
            int s = srcS[j];
            a += b2f(Y1[(size_t)s * 256 + t]) * dinv[s];
        }
        T2[(size_t)n * 256 + t] = f2b(a * di);
    }
}

// ---------------- GEMM1: Y1 = T1(f32)[M,128] @ W1[128,256] -> bf16 (no bias; BN cancels it) ----

__global__ void k_gemm1(const float* __restrict__ A, const float* __restrict__ W,
                        unsigned short* __restrict__ C, int M) {
    __shared__ float As[16][68];
    __shared__ float Ws[16][64];
    int tid = threadIdx.x;
    int tx = tid & 15, ty = tid >> 4;
    int row0 = blockIdx.x * 64, col0 = blockIdx.y * 64;
    int lrow = tid >> 2, lk = (tid & 3) << 2;
    int wk = tid >> 4, wc = (tid & 15) << 2;
    float acc[4][4] = {{0.f}};
    for (int k0 = 0; k0 < 128; k0 += 16) {
        float4 av = make_float4(0.f, 0.f, 0.f, 0.f);
        if (row0 + lrow < M)
            av = *(const float4*)&A[(size_t)(row0 + lrow) * 128 + k0 + lk];
        As[lk + 0][lrow] = av.x; As[lk + 1][lrow] = av.y;
        As[lk + 2][lrow] = av.z; As[lk + 3][lrow] = av.w;
        *(float4*)&Ws[wk][wc] = *(const float4*)&W[(size_t)(k0 + wk) * 256 + col0 + wc];
        __syncthreads();
#pragma unroll
        for (int k = 0; k < 16; k++) {
            float a[4], b[4];
            *(float4*)a = *(float4*)&As[k][ty << 2];
            *(float4*)b = *(float4*)&Ws[k][tx << 2];
#pragma unroll
            for (int i = 0; i < 4; i++)
#pragma unroll
                for (int j = 0; j < 4; j++)
                    acc[i][j] = fmaf(a[i], b[j], acc[i][j]);
        }
        __syncthreads();
    }
#pragma unroll
    for (int i = 0; i < 4; i++) {
        int r = row0 + (ty << 2) + i;
        if (r < M) {
            ushort4 o;
            o.x = f2b(acc[i][0]); o.y = f2b(acc[i][1]);
            o.z = f2b(acc[i][2]); o.w = f2b(acc[i][3]);
            *(ushort4*)&C[(size_t)r * 256 + col0 + (tx << 2)] = o;
        }
    }
}

// ---------------- GEMM2 stats-only: col sums/sumsq of T2(bf16)@W2 (no store, no bias) ----

__global__ void k_gemm2stats(const unsigned short* __restrict__ A, const float* __restrict__ W,
                             float* __restrict__ sums, int M) {
    __shared__ float As[16][68];
    __shared__ float Ws[16][64];
    __shared__ float redS[16][64];
    __shared__ float redQ[16][64];
    int tid = threadIdx.x;
    int tx = tid & 15, ty = tid >> 4;
    int row0 = blockIdx.x * 64, col0 = blockIdx.y * 64;
    int lrow = tid >> 2, lk = (tid & 3) << 2;
    int wk = tid >> 4, wc = (tid & 15) << 2;
    float acc[4][4] = {{0.f}};
    for (int k0 = 0; k0 < 256; k0 += 16) {
        ushort4 a4 = make_ushort4(0, 0, 0, 0);
        if (row0 + lrow < M)
            a4 = *(const ushort4*)&A[(size_t)(row0 + lrow) * 256 + k0 + lk];
        As[lk + 0][lrow] = b2f(a4.x); As[lk + 1][lrow] = b2f(a4.y);
        As[lk + 2][lrow] = b2f(a4.z); As[lk + 3][lrow] = b2f(a4.w);
        *(float4*)&Ws[wk][wc] = *(const float4*)&W[(size_t)(k0 + wk) * 512 + col0 + wc];
        __syncthreads();
#pragma unroll
        for (int k = 0; k < 16; k++) {
            float a[4], b[4];
            *(float4*)a = *(float4*)&As[k][ty << 2];
            *(float4*)b = *(float4*)&Ws[k][tx << 2];
#pragma unroll
            for (int i = 0; i < 4; i++)
#pragma unroll
                for (int j = 0; j < 4; j++)
                    acc[i][j] = fmaf(a[i], b[j], acc[i][j]);
        }
        __syncthreads();
    }
    // padded rows (>=M) have acc==0 -> contribute 0 to both sums: harmless.
#pragma unroll
    for (int j = 0; j < 4; j++) {
        float s = 0.f, q = 0.f;
#pragma unroll
        for (int i = 0; i < 4; i++) { float y = acc[i][j]; s += y; q += y * y; }
        redS[ty][(tx << 2) + j] = s;
        redQ[ty][(tx << 2) + j] = q;
    }
    __syncthreads();
    if (tid < 64) {
        float s = 0.f;
        for (int t = 0; t < 16; t++) s += redS[t][tid];
        atomicAdd(&sums[col0 + tid], s);
    } else if (tid < 128) {
        int c = tid - 64;
        float q = 0.f;
        for (int t = 0; t < 16; t++) q += redQ[t][c];
        atomicAdd(&sums[512 + col0 + c], q);
    }
}

// ---------------- BN params + apply ----------------

__global__ void k_bnparam(float* __restrict__ sums, const float* __restrict__ g,
                          const float* __restrict__ be, int n, int F) {
    int c = blockIdx.x * blockDim.x + threadIdx.x;
    if (c < F) {
        float m = sums[c] / n;
        float v = sums[F + c] / n - m * m;
        float a = g[c] * rsqrtf(v + 1e-5f);
        sums[c] = a;
        sums[F + c] = be[c] - m * a;
    }
}

__global__ void k_colstats_b16(const unsigned short* __restrict__ X, float* __restrict__ sums, int n) {
    int t = threadIdx.x;  // 256, F=256
    int r0 = blockIdx.x * 256;
    int r1 = min(r0 + 256, n);
    float s = 0.f, q = 0.f;
    for (int r = r0; r < r1; r++) {
        float v = b2f(X[(size_t)r * 256 + t]);
        s += v; q += v * v;
    }
    atomicAdd(&sums[t], s);
    atomicAdd(&sums[256 + t], q);
}

__global__ void k_bnleaky_b16(unsigned short* __restrict__ X, const float* __restrict__ p,
                              long long total) {
    long long i = (long long)blockIdx.x * blockDim.x + threadIdx.x;
    long long stride = (long long)gridDim.x * blockDim.x;
    for (; i < total; i += stride) {
        int c = (int)(i & 255);
        float y = b2f(X[i]) * p[c] + p[256 + c];
        X[i] = f2b(LEAKY(y));
    }
}

// ---------------- fused dense: recompute 32-row Y2 slice in LDS, then Wd1/Wd2 chain ----

__global__ void k_dense(const unsigned short* __restrict__ T2, const float* __restrict__ W2,
                        const float* __restrict__ bnp, const float* __restrict__ bd1,
                        const float* __restrict__ Wd1, const float* __restrict__ Wd2,
                        float* __restrict__ logits, int M) {
    __shared__ unsigned short Y2row[32][514];  // bf16, stride 514 -> conflict-free
    __shared__ float As[16][33];
    __shared__ float Ws[16][64];
    __shared__ float sW2[64][6];
    int tid = threadIdx.x;
    int tx = tid & 15, ty = tid >> 4;          // ty 0..15, 2 rows each
    int row0 = blockIdx.x * 32;
    int arow = tid >> 3, ak = (tid & 7) << 1;  // phase-A staging: 32 rows x 16 k
    int wk = tid >> 4, wc = (tid & 15) << 2;

    // ---- phase A: Y2row = leaky(bn(T2row @ W2)) ----
    for (int c0 = 0; c0 < 512; c0 += 64) {
        float acc[2][4] = {{0.f}};
        for (int k0 = 0; k0 < 256; k0 += 16) {
            ushort2 a2 = make_ushort2(0, 0);
            if (row0 + arow < M)
                a2 = *(const ushort2*)&T2[(size_t)(row0 + arow) * 256 + k0 + ak];
            As[ak][arow] = b2f(a2.x);
            As[ak + 1][arow] = b2f(a2.y);
            *(float4*)&Ws[wk][wc] = *(const float4*)&W2[(size_t)(k0 + wk) * 512 + c0 + wc];
            __syncthreads();
#pragma unroll
            for (int k = 0; k < 16; k++) {
                float a0 = As[k][(ty << 1)];
                float a1 = As[k][(ty << 1) + 1];
                float b[4];
                *(float4*)b = *(float4*)&Ws[k][tx << 2];
#pragma unroll
                for (int j = 0; j < 4; j++) {
                    acc[0][j] = fmaf(a0, b[j], acc[0][j]);
                    acc[1][j] = fmaf(a1, b[j], acc[1][j]);
                }
            }
            __syncthreads();
        }
#pragma unroll
        for (int j = 0; j < 4; j++) {
            int c = c0 + (tx << 2) + j;
            float sc = bnp[c], sh = bnp[512 + c];
#pragma unroll
            for (int i = 0; i < 2; i++) {
                float y = fmaf(acc[i][j], sc, sh);
                y = LEAKY(y);
                Y2row[(ty << 1) + i][c] = f2b(y);
            }
        }
        __syncthreads();
    }

    // ---- phase B: logits = leaky(Y2row @ Wd1 + bd1) @ Wd2 ----
    float l[2][6] = {{0.f}};
    for (int col0 = 0; col0 < 4096; col0 += 64) {
        float acc[2][4] = {{0.f}};
        for (int k0 = 0; k0 < 512; k0 += 16) {
            *(float4*)&Ws[wk][wc] = *(const float4*)&Wd1[(size_t)(k0 + wk) * 4096 + col0 + wc];
            __syncthreads();
#pragma unroll
            for (int k = 0; k < 16; k++) {
                float a0 = b2f(Y2row[(ty << 1)][k0 + k]);
                float a1 = b2f(Y2row[(ty << 1) + 1][k0 + k]);
                float b[4];
                *(float4*)b = *(float4*)&Ws[k][tx << 2];
#pragma unroll
                for (int j = 0; j < 4; j++) {
                    acc[0][j] = fmaf(a0, b[j], acc[0][j]);
                    acc[1][j] = fmaf(a1, b[j], acc[1][j]);
                }
            }
            __syncthreads();
        }
        for (int i = tid; i < 384; i += 256)
            sW2[i / 6][i % 6] = Wd2[(size_t)(col0 + i / 6) * 6 + i % 6];
        __syncthreads();
#pragma unroll
        for (int j = 0; j < 4; j++) {
            float bv = bd1[col0 + (tx << 2) + j];
#pragma unroll
            for (int i = 0; i < 2; i++) {
                float t = acc[i][j] + bv;
                t = LEAKY(t);
#pragma unroll
                for (int o = 0; o < 6; o++)
                    l[i][o] = fmaf(t, sW2[(tx << 2) + j][o], l[i][o]);
            }
        }
        __syncthreads();
    }

#pragma unroll
    for (int i = 0; i < 2; i++) {
        int r = row0 + (ty << 1) + i;
#pragma unroll
        for (int o = 0; o < 6; o++) {
            float v = l[i][o];
            v += __shfl_xor(v, 8, 16);
            v += __shfl_xor(v, 4, 16);
            v += __shfl_xor(v, 2, 16);
            v += __shfl_xor(v, 1, 16);
            if (tx == 0 && r < M) logits[(size_t)r * 6 + o] = v;
        }
    }
}

// ---------------- softmax ----------------

__global__ void k_softmax(const float* __restrict__ logits, const float* __restrict__ bd2,
                          float* __restrict__ out, int M) {
    int n = blockIdx.x * blockDim.x + threadIdx.x;
    if (n >= M) return;
    float l[6];
    float mx = -1e30f;
#pragma unroll
    for (int o = 0; o < 6; o++) {
        l[o] = logits[(size_t)n * 6 + o] + bd2[o];
        mx = fmaxf(mx, l[o]);
    }
    float s = 0.f;
#pragma unroll
    for (int o = 0; o < 6; o++) { l[o] = expf(l[o] - mx); s += l[o]; }
    float inv = 1.f / s;
#pragma unroll
    for (int o = 0; o < 6; o++) out[(size_t)n * 6 + o] = l[o] * inv;
}

// ---------------- diagnostic bombs ----------------
// ws too small: out[0] = 2^34 * (1 + ws_size/2^40)  -> decodable ws budget.

__global__ void k_diag_ws(float* __restrict__ out, unsigned long long ws) {
    if (threadIdx.x == 0 && blockIdx.x == 0) {
        float f = (float)((double)ws / 1099511627776.0);
        if (f > 0.999f) f = 0.999f;
        out[0] = ldexpf(1.0f + f, 34);
    }
}

// pipeline anomaly: out[0] = 2^(Ee-30)*(1+m/128), Ee = 64+32+16*b1+8*b2+4*b3+2*b4+b5 >= 96.

__global__ void k_diag(const int* __restrict__ eflag, const int* __restrict__ startM,
                       int E, const float* __restrict__ stash,
                       const float* __restrict__ logits, float* __restrict__ out) {
    if (threadIdx.x != 0 || blockIdx.x != 0) return;
    int b1 = *eflag;
    int b2 = (*startM == E) ? 1 : 0;
    int b3 = (fabsf(stash[0] - stash[1]) > 1e-12f || fabsf(stash[2] - stash[3]) > 1e-12f) ? 1 : 0;
    int b4 = (fabsf(stash[4]) > 1e-12f || fabsf(stash[5]) > 1e-12f ||
              fabsf(stash[6]) > 1e-12f || fabsf(stash[7]) > 1e-12f) ? 1 : 0;
    float d0 = fabsf(logits[0] - logits[6]);
    float d1 = fabsf(logits[0] - logits[1]);
    int b5 = (d0 > 1e-12f && d1 > 1e-12f) ? 1 : 0;
    if (b2 && b3 && b4 && b5) return;  // healthy
    float meanabs = 0.f;
    for (int i = 0; i < 16; i++) meanabs += fabsf(logits[i]);
    meanabs *= (1.f / 16.f);
    int m = (int)(32.f + 8.f * log2f(meanabs + 1e-30f));
    m = m < 0 ? 0 : (m > 127 ? 127 : m);
    int Ee = 96 + 16 * b1 + 8 * b2 + 4 * b3 + 2 * b4 + b5;
    out[0] = ldexpf(1.0f + (float)m / 128.0f, Ee - 30);
}

// ---------------- launch ----------------

extern "C" void kernel_launch(void* const* d_in, const int* in_sizes, int n_in,
                              void* d_out, int out_size, void* d_ws, size_t ws_size,
                              hipStream_t stream) {
    const float* x   = (const float*)d_in[0];
    const int*   ei  = (const int*)d_in[1];
    const float* W1  = (const float*)d_in[2];
    const float* W2  = (const float*)d_in[4];
    const float* g1  = (const float*)d_in[6];
    const float* be1 = (const float*)d_in[7];
    const float* g2  = (const float*)d_in[8];
    const float* be2 = (const float*)d_in[9];
    const float* Wd1 = (const float*)d_in[10];
    const float* bd1 = (const float*)d_in[11];
    const float* Wd2 = (const float*)d_in[12];
    const float* bd2 = (const float*)d_in[13];
    float* out = (float*)d_out;

    const int M = in_sizes[0] / 128;   // 100000
    const int E = in_sizes[1] / 2;     // 3200000

    size_t szA = (size_t)M * 512;      // region A bytes: T1 f32 M*128 | T2 bf16 M*256
    size_t szB = (size_t)M * 512;      // region B bytes: Y1 bf16 M*256 | logits f32 M*6
    size_t csr = (size_t)M * 8 + ((size_t)M + 1) * 8 + (size_t)E * 4 + 8192 + 128;
    size_t need = szA + szB + csr;     // ~116.8 MB

    if (ws_size < need) {
        k_setf<<<2048, 256, 0, stream>>>(out, 0.f, out_size);
        k_diag_ws<<<1, 64, 0, stream>>>(out, (unsigned long long)ws_size);
        return;
    }

    char* base = (char*)d_ws;
    float* T1 = (float*)base;                         // early life
    unsigned short* T2 = (unsigned short*)base;       // late life
    unsigned short* Y1 = (unsigned short*)(base + szA);
    float* logits = (float*)(base + szA);             // after Y1 dead
    char* cb = base + szA + szB;
    float* dinv   = (float*)cb;
    int*   cnt    = (int*)(dinv + M);
    int*   startA = cnt + M;
    int*   cursor = startA + (M + 1);
    int*   srcS   = cursor + (M + 1);
    float* sums   = (float*)(srcS + E);
    int*   eflag  = (int*)(sums + 2048);
    float* stash  = (float*)(eflag + 8);

    int mt  = (M + 63) / 64;
    int mt2 = (M + 31) / 32;
    int nb  = (M + 255) / 256;

    // --- CSR ---
    k_detect<<<1, 256, 0, stream>>>(ei, eflag);
    k_seti<<<2048, 256, 0, stream>>>(cnt, 0, M);
    k_count<<<4096, 256, 0, stream>>>(ei, E, M, eflag, cnt);
    k_dinv<<<nb, 256, 0, stream>>>(cnt, dinv, M);
    k_scan<<<1, 256, 0, stream>>>(cnt, startA, M);
    k_copy_i32<<<nb, 256, 0, stream>>>(startA, cursor, M);
    k_fill<<<4096, 256, 0, stream>>>(ei, E, M, eflag, cursor, srcS);

    // --- layer 1 ---
    k_agg1<<<2048, 128, 0, stream>>>(x, dinv, startA, srcS, T1, M);
    k_stash_f32<<<1, 64, 0, stream>>>(T1, 3, 128 * 7 + 3, 0, 128 * 7, stash);
    k_gemm1<<<dim3(mt, 4), 256, 0, stream>>>(T1, W1, Y1, M);
    k_setf<<<8, 256, 0, stream>>>(sums, 0.f, 2048);
    k_colstats_b16<<<nb, 256, 0, stream>>>(Y1, sums, M);
    k_bnparam<<<1, 256, 0, stream>>>(sums, g1, be1, M, 256);
    k_bnleaky_b16<<<4096, 256, 0, stream>>>(Y1, sums, (long long)M * 256);
    k_stash_b16<<<1, 64, 0, stream>>>(Y1, 5, 77, 256 + 5, 256 * 9 + 5, stash + 4);

    // --- layer 2 (stats-only GEMM; Y2 never materialized) ---
    k_agg2<<<2048, 256, 0, stream>>>(Y1, dinv, startA, srcS, T2, M);
    k_setf<<<8, 256, 0, stream>>>(sums, 0.f, 2048);
    k_gemm2stats<<<dim3(mt, 8), 256, 0, stream>>>(T2, W2, sums, M);
    k_bnparam<<<2, 256, 0, stream>>>(sums, g2, be2, M, 512);

    // --- fused dense (recomputes Y2 slice per block) + softmax ---
    k_dense<<<mt2, 256, 0, stream>>>(T2, W2, sums, bd1, Wd1, Wd2, logits, M);
    k_softmax<<<nb, 256, 0, stream>>>(logits, bd2, out, M);

    // --- anomaly bomb (writes only if a stage looks dead) ---
    k_diag<<<1, 64, 0, stream>>>(eflag, startA + M, E, stash, logits, out);
}

// Round 9
// 3987.811 us; speedup vs baseline: 3.0065x; 3.0065x over previous
//
#include <hip/hip_runtime.h>
#include <math.h>

#define LEAKY(t) ((t) >= 0.0f ? (t) : 0.01f * (t))

typedef __attribute__((ext_vector_type(8))) short bf16x8;
typedef __attribute__((ext_vector_type(4))) float f32x4;

static __device__ __forceinline__ float b2f(unsigned short u) {
    return __uint_as_float(((unsigned)u) << 16);
}
static __device__ __forceinline__ unsigned short f2b(float f) {
    unsigned x = __float_as_uint(f);
    unsigned r = (x + 0x7fffu + ((x >> 16) & 1u)) >> 16;
    return (unsigned short)r;
}

// ---------------- init helpers ----------------

__global__ void k_seti(int* __restrict__ p, int v, int n) {
    int i = blockIdx.x * blockDim.x + threadIdx.x;
    int st = gridDim.x * blockDim.x;
    for (; i < n; i += st) p[i] = v;
}

__global__ void k_setf(float* __restrict__ p, float v, int n) {
    int i = blockIdx.x * blockDim.x + threadIdx.x;
    int st = gridDim.x * blockDim.x;
    for (; i < n; i += st) p[i] = v;
}

__global__ void k_stash_f32(const float* __restrict__ a, int i0, int i1, int i2, int i3,
                            float* __restrict__ dst) {
    if (threadIdx.x == 0 && blockIdx.x == 0) {
        dst[0] = a[i0]; dst[1] = a[i1]; dst[2] = a[i2]; dst[3] = a[i3];
    }
}

__global__ void k_stash_b16(const unsigned short* __restrict__ a, int i0, int i1, int i2, int i3,
                            float* __restrict__ dst) {
    if (threadIdx.x == 0 && blockIdx.x == 0) {
        dst[0] = b2f(a[i0]); dst[1] = b2f(a[i1]); dst[2] = b2f(a[i2]); dst[3] = b2f(a[i3]);
    }
}

// ---------------- edge dtype detection ----------------

__global__ void k_detect(const int* __restrict__ ei, int* __restrict__ flag) {
    __shared__ int nz;
    if (threadIdx.x == 0) nz = 0;
    __syncthreads();
    int acc = 0;
    for (int i = threadIdx.x; i < 1024; i += 256) acc |= ei[2 * i + 1];
    if (acc != 0) atomicOr(&nz, 1);
    __syncthreads();
    if (threadIdx.x == 0) *flag = (nz == 0) ? 1 : 0;
}

// ---------------- CSR build ----------------

__global__ void k_count(const int* __restrict__ ei, int E, int Nn,
                        const int* __restrict__ flag, int* __restrict__ cnt) {
    int f = *flag;
    int i = blockIdx.x * blockDim.x + threadIdx.x;
    int stride = gridDim.x * blockDim.x;
    for (; i < E; i += stride) {
        int d = f ? ei[2 * E + 2 * i] : ei[E + i];
        if ((unsigned)d < (unsigned)Nn) atomicAdd(&cnt[d], 1);
    }
}

__global__ void k_dinv(const int* __restrict__ cnt, float* __restrict__ dinv, int n) {
    int i = blockIdx.x * blockDim.x + threadIdx.x;
    if (i < n) dinv[i] = rsqrtf((float)(cnt[i] + 1));
}

__global__ void k_scan(const int* __restrict__ cnt, int* __restrict__ start, int n) {
    __shared__ int sm[256];
    __shared__ int carry;
    int tid = threadIdx.x;
    if (tid == 0) carry = 0;
    __syncthreads();
    for (int base = 0; base < n; base += 1024) {
        int i0 = base + tid * 4;
        int v0 = (i0 + 0 < n) ? cnt[i0 + 0] : 0;
        int v1 = (i0 + 1 < n) ? cnt[i0 + 1] : 0;
        int v2 = (i0 + 2 < n) ? cnt[i0 + 2] : 0;
        int v3 = (i0 + 3 < n) ? cnt[i0 + 3] : 0;
        int s = v0 + v1 + v2 + v3;
        sm[tid] = s;
        __syncthreads();
        int x = s;
        for (int off = 1; off < 256; off <<= 1) {
            int y = (tid >= off) ? sm[tid - off] : 0;
            __syncthreads();
            x += y;
            sm[tid] = x;
            __syncthreads();
        }
        int e = x - s + carry;
        if (i0 + 0 < n) start[i0 + 0] = e; e += v0;
        if (i0 + 1 < n) start[i0 + 1] = e; e += v1;
        if (i0 + 2 < n) start[i0 + 2] = e; e += v2;
        if (i0 + 3 < n) start[i0 + 3] = e; e += v3;
        __syncthreads();
        if (tid == 255) carry += sm[255];
        __syncthreads();
    }
    if (tid == 0) start[n] = carry;
}

__global__ void k_copy_i32(const int* __restrict__ a, int* __restrict__ b, int n) {
    int i = blockIdx.x * blockDim.x + threadIdx.x;
    if (i < n) b[i] = a[i];
}

__global__ void k_fill(const int* __restrict__ ei, int E, int Nn,
                       const int* __restrict__ flag,
                       int* __restrict__ cursor, int* __restrict__ srcS) {
    int f = *flag;
    int i = blockIdx.x * blockDim.x + threadIdx.x;
    int stride = gridDim.x * blockDim.x;
    for (; i < E; i += stride) {
        int s = f ? ei[2 * i] : ei[i];
        int d = f ? ei[2 * E + 2 * i] : ei[E + i];
        if ((unsigned)d < (unsigned)Nn) {
            int p = atomicAdd(&cursor[d], 1);
            srcS[p] = ((unsigned)s < (unsigned)Nn) ? s : 0;
        }
    }
}

// ---------------- aggregation ----------------

__global__ void k_agg1(const float* __restrict__ x, const float* __restrict__ dinv,
                       const int* __restrict__ start, const int* __restrict__ srcS,
                       float* __restrict__ out, int M) {
    int t = threadIdx.x;  // 128
    for (int n = blockIdx.x; n < M; n += gridDim.x) {
        float di = dinv[n];
        float a = x[(size_t)n * 128 + t] * di;
        int e1 = start[n + 1];
        for (int j = start[n]; j < e1; ++j) {
            int s = srcS[j];
            a += x[(size_t)s * 128 + t] * dinv[s];
        }
        out[(size_t)n * 128 + t] = a * di;
    }
}

__global__ void k_agg2(const unsigned short* __restrict__ Y1, const float* __restrict__ dinv,
                       const int* __restrict__ start, const int* __restrict__ srcS,
                       unsigned short* __restrict__ T2, int M) {
    int t = threadIdx.x;  // 256
    for (int n = blockIdx.x; n < M; n += gridDim.x) {
        float di = dinv[n];
        float a = b2f(Y1[(size_t)n * 256 + t]) * di;
        int e1 = start[n + 1];
        for (int j = start[n]; j < e1; ++j) {
            int s = srcS[j];
            a += b2f(Y1[(size_t)s * 256 + t]) * dinv[s];
        }
        T2[(size_t)n * 256 + t] = f2b(a * di);
    }
}

// ---------------- GEMM1: Y1 = T1(f32)[M,128] @ W1[128,256] -> bf16 ----------------

__global__ void k_gemm1(const float* __restrict__ A, const float* __restrict__ W,
                        unsigned short* __restrict__ C, int M) {
    __shared__ float As[16][68];
    __shared__ float Ws[16][64];
    int tid = threadIdx.x;
    int tx = tid & 15, ty = tid >> 4;
    int row0 = blockIdx.x * 64, col0 = blockIdx.y * 64;
    int lrow = tid >> 2, lk = (tid & 3) << 2;
    int wk = tid >> 4, wc = (tid & 15) << 2;
    float acc[4][4] = {{0.f}};
    for (int k0 = 0; k0 < 128; k0 += 16) {
        float4 av = make_float4(0.f, 0.f, 0.f, 0.f);
        if (row0 + lrow < M)
            av = *(const float4*)&A[(size_t)(row0 + lrow) * 128 + k0 + lk];
        As[lk + 0][lrow] = av.x; As[lk + 1][lrow] = av.y;
        As[lk + 2][lrow] = av.z; As[lk + 3][lrow] = av.w;
        *(float4*)&Ws[wk][wc] = *(const float4*)&W[(size_t)(k0 + wk) * 256 + col0 + wc];
        __syncthreads();
#pragma unroll
        for (int k = 0; k < 16; k++) {
            float a[4], b[4];
            *(float4*)a = *(float4*)&As[k][ty << 2];
            *(float4*)b = *(float4*)&Ws[k][tx << 2];
#pragma unroll
            for (int i = 0; i < 4; i++)
#pragma unroll
                for (int j = 0; j < 4; j++)
                    acc[i][j] = fmaf(a[i], b[j], acc[i][j]);
        }
        __syncthreads();
    }
#pragma unroll
    for (int i = 0; i < 4; i++) {
        int r = row0 + (ty << 2) + i;
        if (r < M) {
            ushort4 o;
            o.x = f2b(acc[i][0]); o.y = f2b(acc[i][1]);
            o.z = f2b(acc[i][2]); o.w = f2b(acc[i][3]);
            *(ushort4*)&C[(size_t)r * 256 + col0 + (tx << 2)] = o;
        }
    }
}

// ---------------- GEMM2 stats-only ----------------

__global__ void k_gemm2stats(const unsigned short* __restrict__ A, const float* __restrict__ W,
                             float* __restrict__ sums, int M) {
    __shared__ float As[16][68];
    __shared__ float Ws[16][64];
    __shared__ float redS[16][64];
    __shared__ float redQ[16][64];
    int tid = threadIdx.x;
    int tx = tid & 15, ty = tid >> 4;
    int row0 = blockIdx.x * 64, col0 = blockIdx.y * 64;
    int lrow = tid >> 2, lk = (tid & 3) << 2;
    int wk = tid >> 4, wc = (tid & 15) << 2;
    float acc[4][4] = {{0.f}};
    for (int k0 = 0; k0 < 256; k0 += 16) {
        ushort4 a4 = make_ushort4(0, 0, 0, 0);
        if (row0 + lrow < M)
            a4 = *(const ushort4*)&A[(size_t)(row0 + lrow) * 256 + k0 + lk];
        As[lk + 0][lrow] = b2f(a4.x); As[lk + 1][lrow] = b2f(a4.y);
        As[lk + 2][lrow] = b2f(a4.z); As[lk + 3][lrow] = b2f(a4.w);
        *(float4*)&Ws[wk][wc] = *(const float4*)&W[(size_t)(k0 + wk) * 512 + col0 + wc];
        __syncthreads();
#pragma unroll
        for (int k = 0; k < 16; k++) {
            float a[4], b[4];
            *(float4*)a = *(float4*)&As[k][ty << 2];
            *(float4*)b = *(float4*)&Ws[k][tx << 2];
#pragma unroll
            for (int i = 0; i < 4; i++)
#pragma unroll
                for (int j = 0; j < 4; j++)
                    acc[i][j] = fmaf(a[i], b[j], acc[i][j]);
        }
        __syncthreads();
    }
#pragma unroll
    for (int j = 0; j < 4; j++) {
        float s = 0.f, q = 0.f;
#pragma unroll
        for (int i = 0; i < 4; i++) { float y = acc[i][j]; s += y; q += y * y; }
        redS[ty][(tx << 2) + j] = s;
        redQ[ty][(tx << 2) + j] = q;
    }
    __syncthreads();
    if (tid < 64) {
        float s = 0.f;
        for (int t = 0; t < 16; t++) s += redS[t][tid];
        atomicAdd(&sums[col0 + tid], s);
    } else if (tid < 128) {
        int c = tid - 64;
        float q = 0.f;
        for (int t = 0; t < 16; t++) q += redQ[t][c];
        atomicAdd(&sums[512 + col0 + c], q);
    }
}

// ---------------- BN ----------------

__global__ void k_bnparam(float* __restrict__ sums, const float* __restrict__ g,
                          const float* __restrict__ be, int n, int F) {
    int c = blockIdx.x * blockDim.x + threadIdx.x;
    if (c < F) {
        float m = sums[c] / n;
        float v = sums[F + c] / n - m * m;
        float a = g[c] * rsqrtf(v + 1e-5f);
        sums[c] = a;
        sums[F + c] = be[c] - m * a;
    }
}

__global__ void k_colstats_b16(const unsigned short* __restrict__ X, float* __restrict__ sums, int n) {
    int t = threadIdx.x;
    int r0 = blockIdx.x * 256;
    int r1 = min(r0 + 256, n);
    float s = 0.f, q = 0.f;
    for (int r = r0; r < r1; r++) {
        float v = b2f(X[(size_t)r * 256 + t]);
        s += v; q += v * v;
    }
    atomicAdd(&sums[t], s);
    atomicAdd(&sums[256 + t], q);
}

__global__ void k_bnleaky_b16(unsigned short* __restrict__ X, const float* __restrict__ p,
                              long long total) {
    long long i = (long long)blockIdx.x * blockDim.x + threadIdx.x;
    long long stride = (long long)gridDim.x * blockDim.x;
    for (; i < total; i += stride) {
        int c = (int)(i & 255);
        float y = b2f(X[i]) * p[c] + p[256 + c];
        X[i] = f2b(LEAKY(y));
    }
}

// ---------------- weight swizzle: f32 [K][N] -> bf16 MFMA B-fragment order ----
// dst[((ct*KO + ko)*64 + lane)*8 + j] = src[ko*32 + (lane>>4)*8 + j][ct*16 + (lane&15)]

__global__ void k_swz(const float* __restrict__ src, unsigned short* __restrict__ dst,
                      int N, int KO) {
    __shared__ float t[32][65];
    int tid = threadIdx.x;
    int ko = blockIdx.x;
    int n0 = blockIdx.y * 64;
    int r = tid >> 3, c8 = (tid & 7) * 8;
    const float* s = src + (size_t)(ko * 32 + r) * N + n0 + c8;
    float4 v0 = *(const float4*)s;
    float4 v1 = *(const float4*)(s + 4);
    t[r][c8 + 0] = v0.x; t[r][c8 + 1] = v0.y; t[r][c8 + 2] = v0.z; t[r][c8 + 3] = v0.w;
    t[r][c8 + 4] = v1.x; t[r][c8 + 5] = v1.y; t[r][c8 + 6] = v1.z; t[r][c8 + 7] = v1.w;
    __syncthreads();
    int cc = tid >> 6, lane = tid & 63;
    int lr = lane & 15, lg = lane >> 4;
    int ct = (n0 >> 4) + cc;
    bf16x8 ov;
#pragma unroll
    for (int j = 0; j < 8; j++) ov[j] = (short)f2b(t[lg * 8 + j][cc * 16 + lr]);
    *(bf16x8*)(dst + ((size_t)(ct * KO + ko) * 64 + lane) * 8) = ov;
}

// ---------------- fused dense, MFMA bf16 ----------------
// block = 64 rows, 4 waves x 16 rows.
// phase A: Y2[64][512] = leaky(bn(T2 @ W2)) via mfma, -> LDS bf16.
// phase B: logits = leaky(Y2 @ Wd1 + bd1) @ Wd2, A-frags in registers.

__global__ void k_dense(const unsigned short* __restrict__ T2,
                        const unsigned short* __restrict__ W2s,
                        const float* __restrict__ bnp,
                        const float* __restrict__ bd1,
                        const unsigned short* __restrict__ Wd1s,
                        const float* __restrict__ Wd2,
                        float* __restrict__ logits, int M) {
    __shared__ unsigned short Y2[64][520];  // stride 520: b128 reads conflict-free
    int tid = threadIdx.x;
    int lane = tid & 63, w = tid >> 6;
    int lr = lane & 15, lg = lane >> 4;
    int row0 = blockIdx.x * 64;

    // ---- phase A ----
    int arow = row0 + w * 16 + lr;
    const unsigned short* T2r = T2 + (size_t)(arow < M ? arow : (M - 1)) * 256;
    bf16x8 a8[8];
#pragma unroll
    for (int ko = 0; ko < 8; ko++)
        a8[ko] = *(const bf16x8*)(T2r + ko * 32 + lg * 8);
    for (int ct = 0; ct < 32; ct++) {
        f32x4 acc = {0.f, 0.f, 0.f, 0.f};
#pragma unroll
        for (int ko = 0; ko < 8; ko++) {
            bf16x8 b = *(const bf16x8*)(W2s + ((size_t)(ct * 8 + ko) * 64 + lane) * 8);
            acc = __builtin_amdgcn_mfma_f32_16x16x32_bf16(a8[ko], b, acc, 0, 0, 0);
        }
        int col = ct * 16 + lr;
        float sc = bnp[col], sh = bnp[512 + col];
#pragma unroll
        for (int i = 0; i < 4; i++) {
            float y = fmaf(acc[i], sc, sh);
            y = LEAKY(y);
            Y2[w * 16 + lg * 4 + i][col] = f2b(y);
        }
    }
    __syncthreads();

    // ---- phase B ----
    bf16x8 p8[16];
#pragma unroll
    for (int ko = 0; ko < 16; ko++)
        p8[ko] = *(const bf16x8*)(&Y2[w * 16 + lr][ko * 32 + lg * 8]);
    float l[4][6] = {{0.f}};
    for (int ct = 0; ct < 256; ct++) {
        f32x4 acc = {0.f, 0.f, 0.f, 0.f};
#pragma unroll
        for (int ko = 0; ko < 16; ko++) {
            bf16x8 b = *(const bf16x8*)(Wd1s + ((size_t)(ct * 16 + ko) * 64 + lane) * 8);
            acc = __builtin_amdgcn_mfma_f32_16x16x32_bf16(p8[ko], b, acc, 0, 0, 0);
        }
        int col = ct * 16 + lr;
        float bv = bd1[col];
        const float* w2r = Wd2 + (size_t)col * 6;
        float u0 = w2r[0], u1 = w2r[1], u2 = w2r[2], u3 = w2r[3], u4 = w2r[4], u5 = w2r[5];
#pragma unroll
        for (int i = 0; i < 4; i++) {
            float t = acc[i] + bv;
            t = LEAKY(t);
            l[i][0] = fmaf(t, u0, l[i][0]);
            l[i][1] = fmaf(t, u1, l[i][1]);
            l[i][2] = fmaf(t, u2, l[i][2]);
            l[i][3] = fmaf(t, u3, l[i][3]);
            l[i][4] = fmaf(t, u4, l[i][4]);
            l[i][5] = fmaf(t, u5, l[i][5]);
        }
    }
#pragma unroll
    for (int i = 0; i < 4; i++) {
        int r = row0 + w * 16 + lg * 4 + i;
#pragma unroll
        for (int o = 0; o < 6; o++) {
            float v = l[i][o];
            v += __shfl_xor(v, 1);
            v += __shfl_xor(v, 2);
            v += __shfl_xor(v, 4);
            v += __shfl_xor(v, 8);
            if (lr == 0 && r < M) logits[(size_t)r * 6 + o] = v;
        }
    }
}

// ---------------- softmax ----------------

__global__ void k_softmax(const float* __restrict__ logits, const float* __restrict__ bd2,
                          float* __restrict__ out, int M) {
    int n = blockIdx.x * blockDim.x + threadIdx.x;
    if (n >= M) return;
    float l[6];
    float mx = -1e30f;
#pragma unroll
    for (int o = 0; o < 6; o++) {
        l[o] = logits[(size_t)n * 6 + o] + bd2[o];
        mx = fmaxf(mx, l[o]);
    }
    float s = 0.f;
#pragma unroll
    for (int o = 0; o < 6; o++) { l[o] = expf(l[o] - mx); s += l[o]; }
    float inv = 1.f / s;
#pragma unroll
    for (int o = 0; o < 6; o++) out[(size_t)n * 6 + o] = l[o] * inv;
}

// ---------------- diagnostic bombs ----------------

__global__ void k_diag_ws(float* __restrict__ out, unsigned long long ws) {
    if (threadIdx.x == 0 && blockIdx.x == 0) {
        float f = (float)((double)ws / 1099511627776.0);
        if (f > 0.999f) f = 0.999f;
        out[0] = ldexpf(1.0f + f, 34);
    }
}

__global__ void k_diag(const int* __restrict__ eflag, const int* __restrict__ startM,
                       int E, const float* __restrict__ stash,
                       const float* __restrict__ logits, float* __restrict__ out) {
    if (threadIdx.x != 0 || blockIdx.x != 0) return;
    int b1 = *eflag;
    int b2 = (*startM == E) ? 1 : 0;
    int b3 = (fabsf(stash[0] - stash[1]) > 1e-12f || fabsf(stash[2] - stash[3]) > 1e-12f) ? 1 : 0;
    int b4 = (fabsf(stash[4]) > 1e-12f || fabsf(stash[5]) > 1e-12f ||
              fabsf(stash[6]) > 1e-12f || fabsf(stash[7]) > 1e-12f) ? 1 : 0;
    float d0 = fabsf(logits[0] - logits[6]);
    float d1 = fabsf(logits[0] - logits[1]);
    int b5 = (d0 > 1e-12f && d1 > 1e-12f) ? 1 : 0;
    if (b2 && b3 && b4 && b5) return;
    float meanabs = 0.f;
    for (int i = 0; i < 16; i++) meanabs += fabsf(logits[i]);
    meanabs *= (1.f / 16.f);
    int m = (int)(32.f + 8.f * log2f(meanabs + 1e-30f));
    m = m < 0 ? 0 : (m > 127 ? 127 : m);
    int Ee = 96 + 16 * b1 + 8 * b2 + 4 * b3 + 2 * b4 + b5;
    out[0] = ldexpf(1.0f + (float)m / 128.0f, Ee - 30);
}

// ---------------- launch ----------------

extern "C" void kernel_launch(void* const* d_in, const int* in_sizes, int n_in,
                              void* d_out, int out_size, void* d_ws, size_t ws_size,
                              hipStream_t stream) {
    const float* x   = (const float*)d_in[0];
    const int*   ei  = (const int*)d_in[1];
    const float* W1  = (const float*)d_in[2];
    const float* W2  = (const float*)d_in[4];
    const float* g1  = (const float*)d_in[6];
    const float* be1 = (const float*)d_in[7];
    const float* g2  = (const float*)d_in[8];
    const float* be2 = (const float*)d_in[9];
    const float* Wd1 = (const float*)d_in[10];
    const float* bd1 = (const float*)d_in[11];
    const float* Wd2 = (const float*)d_in[12];
    const float* bd2 = (const float*)d_in[13];
    float* out = (float*)d_out;

    const int M = in_sizes[0] / 128;   // 100000
    const int E = in_sizes[1] / 2;     // 3200000

    size_t szA = (size_t)M * 512;      // region A: T1 f32 M*128 | T2 bf16 M*256
    size_t szB = (size_t)M * 512;      // region B: Y1 bf16 M*256 | logits + W2s + Wd1s
    size_t csr = (size_t)M * 8 + ((size_t)M + 1) * 8 + (size_t)E * 4 + 8192 + 128;
    size_t need = szA + szB + csr;

    if (ws_size < need) {
        k_setf<<<2048, 256, 0, stream>>>(out, 0.f, out_size);
        k_diag_ws<<<1, 64, 0, stream>>>(out, (unsigned long long)ws_size);
        return;
    }

    char* base = (char*)d_ws;
    float* T1 = (float*)base;                         // early life
    unsigned short* T2 = (unsigned short*)base;       // late life
    unsigned short* Y1 = (unsigned short*)(base + szA);
    float* logits = (float*)(base + szA);             // after Y1 dead (2.4 MB)
    unsigned short* W2s  = (unsigned short*)(base + szA + (size_t)8 * 1024 * 1024);   // 256 KB
    unsigned short* Wd1s = (unsigned short*)(base + szA + (size_t)12 * 1024 * 1024);  // 4 MB
    char* cb = base + szA + szB;
    float* dinv   = (float*)cb;
    int*   cnt    = (int*)(dinv + M);
    int*   startA = cnt + M;
    int*   cursor = startA + (M + 1);
    int*   srcS   = cursor + (M + 1);
    float* sums   = (float*)(srcS + E);
    int*   eflag  = (int*)(sums + 2048);
    float* stash  = (float*)(eflag + 8);

    int mt  = (M + 63) / 64;
    int nb  = (M + 255) / 256;

    // --- CSR ---
    k_detect<<<1, 256, 0, stream>>>(ei, eflag);
    k_seti<<<2048, 256, 0, stream>>>(cnt, 0, M);
    k_count<<<4096, 256, 0, stream>>>(ei, E, M, eflag, cnt);
    k_dinv<<<nb, 256, 0, stream>>>(cnt, dinv, M);
    k_scan<<<1, 256, 0, stream>>>(cnt, startA, M);
    k_copy_i32<<<nb, 256, 0, stream>>>(startA, cursor, M);
    k_fill<<<4096, 256, 0, stream>>>(ei, E, M, eflag, cursor, srcS);

    // --- layer 1 ---
    k_agg1<<<2048, 128, 0, stream>>>(x, dinv, startA, srcS, T1, M);
    k_stash_f32<<<1, 64, 0, stream>>>(T1, 3, 128 * 7 + 3, 0, 128 * 7, stash);
    k_gemm1<<<dim3(mt, 4), 256, 0, stream>>>(T1, W1, Y1, M);
    k_setf<<<8, 256, 0, stream>>>(sums, 0.f, 2048);
    k_colstats_b16<<<nb, 256, 0, stream>>>(Y1, sums, M);
    k_bnparam<<<1, 256, 0, stream>>>(sums, g1, be1, M, 256);
    k_bnleaky_b16<<<4096, 256, 0, stream>>>(Y1, sums, (long long)M * 256);
    k_stash_b16<<<1, 64, 0, stream>>>(Y1, 5, 77, 256 + 5, 256 * 9 + 5, stash + 4);

    // --- layer 2: agg -> T2; Y1 now dead -> swizzle weights into region B ---
    k_agg2<<<2048, 256, 0, stream>>>(Y1, dinv, startA, srcS, T2, M);
    k_swz<<<dim3(8, 8), 256, 0, stream>>>(W2, W2s, 512, 8);      // K=256 -> KO=8
    k_swz<<<dim3(16, 64), 256, 0, stream>>>(Wd1, Wd1s, 4096, 16); // K=512 -> KO=16
    k_setf<<<8, 256, 0, stream>>>(sums, 0.f, 2048);
    k_gemm2stats<<<dim3(mt, 8), 256, 0, stream>>>(T2, W2, sums, M);
    k_bnparam<<<2, 256, 0, stream>>>(sums, g2, be2, M, 512);

    // --- fused dense (MFMA) + softmax ---
    k_dense<<<mt, 256, 0, stream>>>(T2, W2s, sums, bd1, Wd1s, Wd2, logits, M);
    k_softmax<<<nb, 256, 0, stream>>>(logits, bd2, out, M);

    // --- anomaly bomb (writes only if a stage looks dead) ---
    k_diag<<<1, 64, 0, stream>>>(eflag, startA + M, E, stash, logits, out);
}